// Round 12
// baseline (1789.297 us; speedup 1.0000x reference)
//
#include <hip/hip_runtime.h>
#include <math.h>

#define N_TOKENS 32768
#define DIM      4096
#define NE       64
#define TM       64              // tokens per block
#define BK       128             // K-chunk
#define KHALF    (DIM / 2)       // 2048
#define NBLK_MAIN (N_TOKENS / TM * 2)   // 1024 (x2 for K-split)
#define NBLK_POST (N_TOKENS / 256)      // 128
#define EPS_GAP  2e-3f
#define REFINE_BLOCKS 1024

// d_out layout (float32 elements):
//   [0, 65536)        weights  [N_TOKENS][2]
//   [65536, 131072)   indices  [N_TOKENS][2]  stored as float
//   [131072, 131136)  new_bias [64]
//
// d_ws layout (4-byte units):
//   [0, 64)              ews_refine[64]  (float, zeroed per call)
//   [64]                 worklist count  (uint, zeroed per call)
//   [128, 8320)          per-post-block expert partials [128][64] (float)
//   [16384, 49152)       worklist token ids (int)
//   [65664, 327808)      W fragments: whi then wlo (bf16, 512KB each)
//   [524288, 4718592)    partial scores psc[2][N_TOKENS][64] (f32, 16.8MB)
//   [5600000, 6700000)   probe dump regions
#define WOFF     65664
#define WL_OFF   16384
#define PART_OFF 128
#define PSC_OFF  524288
#define WFRAG_ELEMS (512 * 512)   // 262144 bf16 per plane

typedef __bf16 bf16x8 __attribute__((ext_vector_type(8)));
typedef float  f32x16 __attribute__((ext_vector_type(16)));

// Convert W [64][4096] f32 -> fragment-ordered bf16 hi/lo.
__global__ __launch_bounds__(256) void prep_w(
    const float* __restrict__ w, float* __restrict__ ws)
{
    __bf16* whi = (__bf16*)(ws + WOFF);
    __bf16* wlo = whi + WFRAG_ELEMS;
    const int tid  = blockIdx.x * 256 + threadIdx.x;  // 0..32767
    const int f    = tid >> 6, lane = tid & 63;
    const int nt   = f & 1,    K16  = f >> 1;
    const int e    = nt * 32 + (lane & 31);
    const int k    = K16 * 16 + (lane >> 5) * 8;
    const float4 a = *(const float4*)(w + (size_t)e * DIM + k);
    const float4 b = *(const float4*)(w + (size_t)e * DIM + k + 4);
    const float v[8] = {a.x, a.y, a.z, a.w, b.x, b.y, b.z, b.w};
    __bf16 h[8], l[8];
    #pragma unroll
    for (int i = 0; i < 8; ++i) {
        h[i] = (__bf16)v[i];
        l[i] = (__bf16)(v[i] - (float)h[i]);
    }
    *(bf16x8*)(whi + (size_t)tid * 8) = *(bf16x8*)h;
    *(bf16x8*)(wlo + (size_t)tid * 8) = *(bf16x8*)l;
}

__device__ __forceinline__ unsigned pack_pair(float f0, float f1, float& r0, float& r1) {
    const unsigned u0 = __float_as_uint(f0), u1 = __float_as_uint(f1);
    const unsigned h0 = u0 & 0xFFFF0000u,   h1 = u1 & 0xFFFF0000u;
    r0 = f0 - __uint_as_float(h0);
    r1 = f1 - __uint_as_float(h1);
    return (u0 >> 16) | h1;
}
__device__ __forceinline__ void cvt_split4(const float4 v, uint2& h, uint2& l) {
    float r0, r1, r2, r3;
    h.x = pack_pair(v.x, v.y, r0, r1);
    h.y = pack_pair(v.z, v.w, r2, r3);
    l.x = (__float_as_uint(r0) >> 16) | (__float_as_uint(r1) & 0xFFFF0000u);
    l.y = (__float_as_uint(r2) >> 16) | (__float_as_uint(r3) & 0xFFFF0000u);
}

// Split-K GEMM (R4 structure, best-so-far): block b = tokens [tb,tb+64),
// K-half kh = b&1. Writes partial scores psc[kh][tok][e].
__global__ __launch_bounds__(256, 4) void gate_main(
    const float* __restrict__ x, float* __restrict__ ws)
{
    __shared__ __align__(16) unsigned char smem[32768];

    const __bf16* whi = (const __bf16*)(ws + WOFF);
    const __bf16* wlo = whi + WFRAG_ELEMS;
    float*        psc = ws + PSC_OFF;

    const int t    = threadIdx.x;
    const int lane = t & 63;
    const int wave = t >> 6;
    const int mt   = wave >> 1;
    const int nt   = wave & 1;
    const int kh   = blockIdx.x & 1;
    const int tb   = (blockIdx.x >> 1) * TM;
    const int kbeg = kh * KHALF;

    const int q     = t & 31;
    const int rbase = t >> 5;

    f32x16 acc0, acc12;
    #pragma unroll
    for (int i = 0; i < 16; ++i) { acc0[i] = 0.f; acc12[i] = 0.f; }

    float4 xv[8];
    #pragma unroll
    for (int j = 0; j < 8; ++j)
        xv[j] = *(const float4*)(x + (size_t)(tb + rbase + 8 * j) * DIM + kbeg + q * 4);

    const int tok0  = mt * 32 + (lane & 31);
    const int klane = lane >> 5;
    const int abase = tok0 * 256;
    const int aswz  = (tok0 & 7) << 4;

    for (int kc = kbeg; kc < kbeg + KHALF; kc += BK) {
        #pragma unroll
        for (int j = 0; j < 8; ++j) {
            const int r = rbase + 8 * j;
            uint2 h, l;
            cvt_split4(xv[j], h, l);
            const int off = r * 256 + ((q * 8) ^ ((r & 7) << 4));
            *(uint2*)(&smem[off])         = h;
            *(uint2*)(&smem[16384 + off]) = l;
        }
        __syncthreads();

        if (kc + BK < kbeg + KHALF) {
            #pragma unroll
            for (int j = 0; j < 8; ++j)
                xv[j] = *(const float4*)(x + (size_t)(tb + rbase + 8 * j) * DIM + kc + BK + q * 4);
        }

        const int K16c = kc >> 4;
        #pragma unroll
        for (int ks = 0; ks < 8; ++ks) {
            const int aoff = abase + ((ks * 32 + klane * 16) ^ aswz);
            const bf16x8 ah = *(const bf16x8*)(&smem[aoff]);
            const bf16x8 al = *(const bf16x8*)(&smem[16384 + aoff]);
            const size_t bidx = ((size_t)((K16c + ks) * 2 + nt) * 64 + lane) * 8;
            const bf16x8 bh = *(const bf16x8*)(whi + bidx);
            const bf16x8 bl = *(const bf16x8*)(wlo + bidx);
            acc0  = __builtin_amdgcn_mfma_f32_32x32x16_bf16(ah, bh, acc0,  0, 0, 0);
            acc12 = __builtin_amdgcn_mfma_f32_32x32x16_bf16(al, bh, acc12, 0, 0, 0);
            acc12 = __builtin_amdgcn_mfma_f32_32x32x16_bf16(ah, bl, acc12, 0, 0, 0);
        }
        __syncthreads();
    }

    const int e = nt * 32 + (lane & 31);
    float* base = psc + (size_t)kh * N_TOKENS * NE;
    #pragma unroll
    for (int r = 0; r < 16; ++r) {
        const int tok = mt * 32 + (r & 3) + 8 * (r >> 2) + 4 * (lane >> 5);
        base[(size_t)(tb + tok) * NE + e] = acc0[r] + acc12[r];
    }
}

// Sum K-halves + bias, top-3 scan, risky-flag or write outputs; expert partials.
__global__ __launch_bounds__(256) void gate_post(
    const float* __restrict__ bias,
    float* __restrict__ out,
    float* __restrict__ ws)
{
    __shared__ float sbias[NE];
    __shared__ float part[NE];
    unsigned* wl_count = (unsigned*)(ws + 64);
    float*    partials = ws + PART_OFF;
    int*      wl       = (int*)(ws + WL_OFF);
    const float* psc   = ws + PSC_OFF;
    const size_t PL    = (size_t)N_TOKENS * NE;

    const int t = threadIdx.x;
    if (t < NE) { sbias[t] = bias[t]; part[t] = 0.f; }
    __syncthreads();

    const int tok = blockIdx.x * 256 + t;
    const float* p = psc + (size_t)tok * NE;

    float v1 = -3e38f, v2 = -3e38f, v3 = -3e38f;
    int   i1 = 0,      i2 = 0;
    #pragma unroll
    for (int g = 0; g < 16; ++g) {
        const float4 a = *(const float4*)(p + g * 4);
        const float4 b = *(const float4*)(p + PL + g * 4);
        float sv4[4] = {a.x + b.x, a.y + b.y, a.z + b.z, a.w + b.w};
        #pragma unroll
        for (int j = 0; j < 4; ++j) {
            const float sv = sv4[j] + sbias[g * 4 + j];
            const int   e  = g * 4 + j;
            if (sv > v1)      { v3 = v2; v2 = v1; i2 = i1; v1 = sv; i1 = e; }
            else if (sv > v2) { v3 = v2; v2 = sv; i2 = e; }
            else if (sv > v3) { v3 = sv; }
        }
    }
    const bool risky = (v1 - v2 < EPS_GAP) || (v2 - v3 < EPS_GAP);
    if (risky) {
        const int pos = (int)atomicAdd(wl_count, 1u);
        wl[pos] = tok;
    } else {
        const float ex = expf(v2 - v1);
        const float w1 = 1.f / (1.f + ex);
        const float w2 = ex * w1;
        const size_t g = (size_t)tok * 2;
        *(float2*)(out + g)                        = make_float2(w1, w2);
        *(float2*)(out + (size_t)N_TOKENS * 2 + g) = make_float2((float)i1, (float)i2);
        atomicAdd(&part[i1], w1);
        atomicAdd(&part[i2], w2);
    }
    __syncthreads();
    if (t < NE) partials[(size_t)blockIdx.x * NE + t] = part[t];
}

// fp64 re-score of near-tie tokens.
__global__ __launch_bounds__(256) void gate_refine(
    const float* __restrict__ x,
    const float* __restrict__ w,
    const float* __restrict__ bias,
    float* __restrict__ out,
    float* __restrict__ ws)
{
    float*          ews_ref  = ws;
    const unsigned* wl_count = (const unsigned*)(ws + 64);
    const int*      wl       = (const int*)(ws + WL_OFF);

    const int t = threadIdx.x;
    const int e = t >> 2;
    const int q = t & 3;
    __shared__ double sc[NE];

    const unsigned count = *wl_count;
    for (unsigned it = blockIdx.x; it < count; it += gridDim.x) {
        const int tok = wl[it];
        const float* xr = x + (size_t)tok * DIM;
        const float* wr = w + (size_t)e * DIM;
        double s = 0.0;
        const int k0 = q * (DIM / 4), k1 = k0 + DIM / 4;
        for (int k = k0; k < k1; k += 4) {
            const float4 a = *(const float4*)(xr + k);
            const float4 b = *(const float4*)(wr + k);
            s += (double)a.x * (double)b.x;
            s += (double)a.y * (double)b.y;
            s += (double)a.z * (double)b.z;
            s += (double)a.w * (double)b.w;
        }
        s += __shfl_xor(s, 1);
        s += __shfl_xor(s, 2);
        if (q == 0) sc[e] = s + (double)bias[e];
        __syncthreads();

        if (t == 0) {
            double v1 = -1e300, v2 = -1e300;
            int i1 = 0, i2 = 0;
            for (int j = 0; j < NE; ++j) {
                const double sv = sc[j];
                if (sv > v1)      { v2 = v1; i2 = i1; v1 = sv; i1 = j; }
                else if (sv > v2) { v2 = sv; i2 = j; }
            }
            const double ex = exp(v2 - v1);
            const double w1 = 1.0 / (1.0 + ex);
            const double w2 = ex * w1;
            const size_t g = (size_t)tok * 2;
            *(float2*)(out + g)                        = make_float2((float)w1, (float)w2);
            *(float2*)(out + (size_t)N_TOKENS * 2 + g) = make_float2((float)i1, (float)i2);
            atomicAdd(&ews_ref[i1], (float)w1);
            atomicAdd(&ews_ref[i2], (float)w2);
        }
        __syncthreads();
    }
}

__global__ void gate_bias(
    const float* __restrict__ bias,
    const float* __restrict__ target,
    const float* __restrict__ ws,
    float* __restrict__ out)
{
    const int e = threadIdx.x;
    const float* partials = ws + PART_OFF;
    float v = ws[e];
    for (int b = 0; b < NBLK_POST; ++b) v += partials[(size_t)b * NE + e];
    float total = v;
    #pragma unroll
    for (int off = 32; off > 0; off >>= 1)
        total += __shfl_xor(total, off);
    const float nb = bias[e] + 0.001f * ((target[e] * total - v) / total);
    out[(size_t)N_TOKENS * 4 + e] = nb;
}

// ================= ABLATION PROBES (sacrificial round) =================

// A) Full R4 pipeline, 4 passes: direct counters on the GEMM structure.
__global__ __launch_bounds__(256, 4) void probe_pipe(
    const float* __restrict__ x, float* __restrict__ ws)
{
    __shared__ __align__(16) unsigned char smem[32768];
    const __bf16* whi = (const __bf16*)(ws + WOFF);
    const __bf16* wlo = whi + WFRAG_ELEMS;

    const int t    = threadIdx.x;
    const int lane = t & 63;
    const int wave = t >> 6;
    const int mt   = wave >> 1;
    const int nt   = wave & 1;
    const int q     = t & 31;
    const int rbase = t >> 5;
    const int tok0  = mt * 32 + (lane & 31);
    const int klane = lane >> 5;
    const int abase = tok0 * 256;
    const int aswz  = (tok0 & 7) << 4;

    f32x16 acc0, acc12;
    #pragma unroll
    for (int i = 0; i < 16; ++i) { acc0[i] = 0.f; acc12[i] = 0.f; }

    for (int pass = 0; pass < 4; ++pass) {
        const int b    = (int)((blockIdx.x + pass * 257u) & 1023u);
        const int kh   = b & 1;
        const int tb   = (b >> 1) * TM;
        const int kbeg = kh * KHALF;

        float4 xv[8];
        #pragma unroll
        for (int j = 0; j < 8; ++j)
            xv[j] = *(const float4*)(x + (size_t)(tb + rbase + 8 * j) * DIM + kbeg + q * 4);

        for (int kc = kbeg; kc < kbeg + KHALF; kc += BK) {
            #pragma unroll
            for (int j = 0; j < 8; ++j) {
                const int r = rbase + 8 * j;
                uint2 h, l;
                cvt_split4(xv[j], h, l);
                const int off = r * 256 + ((q * 8) ^ ((r & 7) << 4));
                *(uint2*)(&smem[off])         = h;
                *(uint2*)(&smem[16384 + off]) = l;
            }
            __syncthreads();
            if (kc + BK < kbeg + KHALF) {
                #pragma unroll
                for (int j = 0; j < 8; ++j)
                    xv[j] = *(const float4*)(x + (size_t)(tb + rbase + 8 * j) * DIM + kc + BK + q * 4);
            }
            const int K16c = kc >> 4;
            #pragma unroll
            for (int ks = 0; ks < 8; ++ks) {
                const int aoff = abase + ((ks * 32 + klane * 16) ^ aswz);
                const bf16x8 ah = *(const bf16x8*)(&smem[aoff]);
                const bf16x8 al = *(const bf16x8*)(&smem[16384 + aoff]);
                const size_t bidx = ((size_t)((K16c + ks) * 2 + nt) * 64 + lane) * 8;
                const bf16x8 bh = *(const bf16x8*)(whi + bidx);
                const bf16x8 bl = *(const bf16x8*)(wlo + bidx);
                acc0  = __builtin_amdgcn_mfma_f32_32x32x16_bf16(ah, bh, acc0,  0, 0, 0);
                acc12 = __builtin_amdgcn_mfma_f32_32x32x16_bf16(al, bh, acc12, 0, 0, 0);
                acc12 = __builtin_amdgcn_mfma_f32_32x32x16_bf16(ah, bl, acc12, 0, 0, 0);
            }
            __syncthreads();
        }
    }
    float s = 0.f;
    #pragma unroll
    for (int r = 0; r < 16; ++r) s += acc0[r] + acc12[r];
    ws[6400000 + (size_t)blockIdx.x * 256 + t] = s;
}

// B) Staging side only: x loads (depth-2 reg pipeline) + cvt + LDS writes +
//    2 syncs/chunk. No B, no MFMA. 4 passes.
__global__ __launch_bounds__(256, 4) void probe_stagelds(
    const float* __restrict__ x, float* __restrict__ ws)
{
    __shared__ __align__(16) unsigned char smem[32768];
    const int t = threadIdx.x;
    const int q = t & 31, rbase = t >> 5;

    for (int pass = 0; pass < 4; ++pass) {
        const int b    = (int)((blockIdx.x + pass * 257u) & 1023u);
        const int kh   = b & 1;
        const int tb   = (b >> 1) * TM;
        const int kbeg = kh * KHALF;

        float4 xvA[8], xvB[8];
        #pragma unroll
        for (int j = 0; j < 8; ++j)
            xvA[j] = *(const float4*)(x + (size_t)(tb + rbase + 8 * j) * DIM + kbeg + q * 4);
        #pragma unroll
        for (int j = 0; j < 8; ++j)
            xvB[j] = *(const float4*)(x + (size_t)(tb + rbase + 8 * j) * DIM + kbeg + BK + q * 4);

        for (int kc = 0; kc < KHALF; kc += 2 * BK) {
            #pragma unroll
            for (int j = 0; j < 8; ++j) {
                const int r = rbase + 8 * j;
                uint2 h, l;
                cvt_split4(xvA[j], h, l);
                const int off = r * 256 + ((q * 8) ^ ((r & 7) << 4));
                *(uint2*)(&smem[off])         = h;
                *(uint2*)(&smem[16384 + off]) = l;
            }
            __syncthreads();
            if (kc + 2 * BK < KHALF) {
                #pragma unroll
                for (int j = 0; j < 8; ++j)
                    xvA[j] = *(const float4*)(x + (size_t)(tb + rbase + 8 * j) * DIM + kbeg + kc + 2 * BK + q * 4);
            }
            __syncthreads();
            #pragma unroll
            for (int j = 0; j < 8; ++j) {
                const int r = rbase + 8 * j;
                uint2 h, l;
                cvt_split4(xvB[j], h, l);
                const int off = r * 256 + ((q * 8) ^ ((r & 7) << 4));
                *(uint2*)(&smem[off])         = h;
                *(uint2*)(&smem[16384 + off]) = l;
            }
            __syncthreads();
            if (kc + 3 * BK < KHALF) {
                #pragma unroll
                for (int j = 0; j < 8; ++j)
                    xvB[j] = *(const float4*)(x + (size_t)(tb + rbase + 8 * j) * DIM + kbeg + kc + 3 * BK + q * 4);
            }
            __syncthreads();
        }
    }
    __syncthreads();
    const float s = ((const float*)smem)[t] + ((const float*)smem)[4096 + t];
    ws[5600000 + (size_t)blockIdx.x * 256 + t] = s;
}

// C) Consumption side only: NO global x reads (synthetic regs, perturbed to
//    defeat hoisting), full cvt + LDS write/read + B(L2) + MFMA + syncs. 12 passes.
__global__ __launch_bounds__(256, 4) void probe_compute(float* __restrict__ ws)
{
    __shared__ __align__(16) unsigned char smem[32768];
    const __bf16* whi = (const __bf16*)(ws + WOFF);
    const __bf16* wlo = whi + WFRAG_ELEMS;

    const int t    = threadIdx.x;
    const int lane = t & 63;
    const int wave = t >> 6;
    const int mt   = wave >> 1;
    const int nt   = wave & 1;
    const int q     = t & 31;
    const int rbase = t >> 5;
    const int tok0  = mt * 32 + (lane & 31);
    const int klane = lane >> 5;
    const int abase = tok0 * 256;
    const int aswz  = (tok0 & 7) << 4;

    float4 xv[8];
    #pragma unroll
    for (int j = 0; j < 8; ++j)
        xv[j] = make_float4(q * 0.013f + j, rbase * 0.007f - j * 0.1f,
                            0.5f - j * 0.03f, 1.0f + q * 0.001f);

    f32x16 acc0, acc12;
    #pragma unroll
    for (int i = 0; i < 16; ++i) { acc0[i] = 0.f; acc12[i] = 0.f; }

    for (int pass = 0; pass < 12; ++pass) {
        for (int kc = 0; kc < KHALF; kc += BK) {
            #pragma unroll
            for (int j = 0; j < 8; ++j) {
                xv[j].x = __uint_as_float(__float_as_uint(xv[j].x) ^ (unsigned)(kc + j + 1));
                const int r = rbase + 8 * j;
                uint2 h, l;
                cvt_split4(xv[j], h, l);
                const int off = r * 256 + ((q * 8) ^ ((r & 7) << 4));
                *(uint2*)(&smem[off])         = h;
                *(uint2*)(&smem[16384 + off]) = l;
            }
            __syncthreads();
            const int K16c = kc >> 4;
            #pragma unroll
            for (int ks = 0; ks < 8; ++ks) {
                const int aoff = abase + ((ks * 32 + klane * 16) ^ aswz);
                const bf16x8 ah = *(const bf16x8*)(&smem[aoff]);
                const bf16x8 al = *(const bf16x8*)(&smem[16384 + aoff]);
                const size_t bidx = ((size_t)((K16c + ks) * 2 + nt) * 64 + lane) * 8;
                const bf16x8 bh = *(const bf16x8*)(whi + bidx);
                const bf16x8 bl = *(const bf16x8*)(wlo + bidx);
                acc0  = __builtin_amdgcn_mfma_f32_32x32x16_bf16(ah, bh, acc0,  0, 0, 0);
                acc12 = __builtin_amdgcn_mfma_f32_32x32x16_bf16(al, bh, acc12, 0, 0, 0);
                acc12 = __builtin_amdgcn_mfma_f32_32x32x16_bf16(ah, bl, acc12, 0, 0, 0);
            }
            __syncthreads();
        }
    }
    float s = 0.f;
    #pragma unroll
    for (int r = 0; r < 16; ++r) s += acc0[r] + acc12[r];
    ws[6000000 + (size_t)blockIdx.x * 256 + t] = s;
}

extern "C" void kernel_launch(void* const* d_in, const int* in_sizes, int n_in,
                              void* d_out, int out_size, void* d_ws, size_t ws_size,
                              hipStream_t stream) {
    const float* x      = (const float*)d_in[0];
    const float* w      = (const float*)d_in[1];
    const float* bias   = (const float*)d_in[2];
    const float* target = (const float*)d_in[3];
    float* out = (float*)d_out;
    float* ws  = (float*)d_ws;

    hipMemsetAsync(ws, 0, 128 * sizeof(float), stream);   // ews_ref + wl_count
    prep_w     <<<128, 256, 0, stream>>>(w, ws);
    gate_main  <<<NBLK_MAIN, 256, 0, stream>>>(x, ws);
    gate_post  <<<NBLK_POST, 256, 0, stream>>>(bias, out, ws);
    gate_refine<<<REFINE_BLOCKS, 256, 0, stream>>>(x, w, bias, out, ws);
    gate_bias  <<<1, 64, 0, stream>>>(bias, target, ws, out);

    // ablation probes (run after all output-producing kernels; deterministic)
    probe_pipe    <<<1024, 256, 0, stream>>>(x, ws);
    probe_stagelds<<<1024, 256, 0, stream>>>(x, ws);
    probe_compute <<<1024, 256, 0, stream>>>(ws);
}